// Round 4
// baseline (126.683 us; speedup 1.0000x reference)
//
#include <hip/hip_runtime.h>
#include <stdint.h>

#define NALL 1024
#define NH   512
#define NCOL 8
#define ROWS_PER_BLOCK 64
#define THREADS 256
#define CHUNKS (NALL / ROWS_PER_BLOCK)   // 16
#define DEPTH 8                          // per-wave LDS ring depth (rows in flight)

typedef float f32x4 __attribute__((ext_vector_type(4)));

// async global->LDS DMA, 16 B per lane (1 KB per wave per instruction).
// LDS dest is wave-uniform base + lane*16; global src is per-lane.
__device__ __forceinline__ void load_to_lds16(const float* gp, float* lds_base) {
    __builtin_amdgcn_global_load_lds(
        (const __attribute__((address_space(1))) uint32_t*)gp,
        (__attribute__((address_space(3))) uint32_t*)lds_base,
        16, 0, 0);
}

// Fused kernel: per-block recompute of joint column norms of concat(u,v)
// (32 KB, L2-resident), then streaming quadratic-form reduction over this
// block's 64 rows of one sample's 1024x1024 Jacobian, with x staged through
// a per-wave LDS ring via global_load_lds DMA (in-flight bytes decoupled
// from VGPR budget -> full HBM BW).
// out[b][q*8+c], q = ih + 2*jh.
__global__ __launch_bounds__(THREADS) void jxy_kernel(
    const float* __restrict__ x, const float* __restrict__ u,
    const float* __restrict__ v, float* __restrict__ out) {
    const int bid   = blockIdx.x;
    const int b     = bid >> 4;          // sample
    const int chunk = bid & (CHUNKS - 1);
    const int r0    = chunk * ROWS_PER_BLOCK;
    const int ih    = (r0 >= NH) ? 1 : 0;   // 64-row chunks never straddle halves
    const int rloc  = r0 - ih * NH;

    const int tid  = threadIdx.x;
    const int wave = tid >> 6;
    const int lane = tid & 63;
    const int jbase = wave * 256 + lane * 4;   // this lane's 4 fixed j positions
    const int jh    = (jbase >= NH) ? 1 : 0;   // uniform per wave
    const int jloc  = jbase - jh * NH;

    // ---- phase 1: joint column norms of concat(u,v) ----
    __shared__ float red[THREADS];
    __shared__ float inv_norm[NCOL];
    {
        const int c   = tid & 7;
        const int seg = tid >> 3;    // 0..31
        float s = 0.f;
        for (int r = seg; r < NH; r += 32) {
            float a = u[r * NCOL + c];
            float bb = v[r * NCOL + c];
            s = fmaf(a, a, fmaf(bb, bb, s));
        }
        red[tid] = s;
        __syncthreads();
        for (int off = THREADS / 2; off >= NCOL; off >>= 1) {
            if (tid < off) red[tid] += red[tid + off];
            __syncthreads();
        }
        if (tid < NCOL) inv_norm[tid] = 1.0f / sqrtf(red[tid]);
        __syncthreads();
    }

    // ---- phase 2: stage normalized left rows (LDS) + right fragment (regs) ----
    __shared__ __align__(16) float wl[ROWS_PER_BLOCK * NCOL];
    const float* rawl = ih ? v : u;
    for (int idx = tid; idx < ROWS_PER_BLOCK * NCOL; idx += THREADS)
        wl[idx] = rawl[rloc * NCOL + idx] * inv_norm[idx & 7];

    const float* rawr = jh ? v : u;
    float wr[4][NCOL];
#pragma unroll
    for (int k = 0; k < 4; ++k) {
        const float4* p = reinterpret_cast<const float4*>(rawr + (size_t)(jloc + k) * NCOL);
        float4 a = p[0];
        float4 bq = p[1];
        wr[k][0] = a.x * inv_norm[0];  wr[k][1] = a.y * inv_norm[1];
        wr[k][2] = a.z * inv_norm[2];  wr[k][3] = a.w * inv_norm[3];
        wr[k][4] = bq.x * inv_norm[4]; wr[k][5] = bq.y * inv_norm[5];
        wr[k][6] = bq.z * inv_norm[6]; wr[k][7] = bq.w * inv_norm[7];
    }
    __syncthreads();   // drains all prior vmem/lds; vmcnt==0 entering the pipeline

    // ---- phase 3: stream 64 rows of x through per-wave LDS ring (DMA) ----
    // ring[wave]: 8 slots x 1 KB. Each wave stages & consumes ONLY its own
    // slice -> no cross-wave deps, no barriers in the loop.
    __shared__ __align__(16) float ring[4][DEPTH][256];

    float acc[NCOL];
#pragma unroll
    for (int c = 0; c < NCOL; ++c) acc[c] = 0.f;

    const float* xrow = x + ((size_t)b * NALL + r0) * NALL + jbase;  // per-lane
    float* ring_base = &ring[wave][0][0];                            // wave-uniform

    // prologue: fill the ring (8 x 1 KB in flight per wave)
#pragma unroll
    for (int s = 0; s < DEPTH; ++s)
        load_to_lds16(xrow + (size_t)s * NALL, ring_base + s * 256);

#define COMPUTE_ROW(r)                                                        \
    {                                                                         \
        f32x4 xv = *reinterpret_cast<const f32x4*>(                           \
            &ring[wave][(r) & (DEPTH - 1)][lane * 4]);                        \
        float t[NCOL];                                                        \
        _Pragma("unroll")                                                     \
        for (int c = 0; c < NCOL; ++c)                                        \
            t[c] = fmaf(xv.x, wr[0][c],                                       \
                   fmaf(xv.y, wr[1][c],                                       \
                   fmaf(xv.z, wr[2][c],                                       \
                        xv.w * wr[3][c])));                                   \
        float4 wa = *reinterpret_cast<const float4*>(&wl[(r) * NCOL]);        \
        float4 wb = *reinterpret_cast<const float4*>(&wl[(r) * NCOL + 4]);    \
        acc[0] = fmaf(wa.x, t[0], acc[0]);                                    \
        acc[1] = fmaf(wa.y, t[1], acc[1]);                                    \
        acc[2] = fmaf(wa.z, t[2], acc[2]);                                    \
        acc[3] = fmaf(wa.w, t[3], acc[3]);                                    \
        acc[4] = fmaf(wb.x, t[4], acc[4]);                                    \
        acc[5] = fmaf(wb.y, t[5], acc[5]);                                    \
        acc[6] = fmaf(wb.z, t[6], acc[6]);                                    \
        acc[7] = fmaf(wb.w, t[7], acc[7]);                                    \
    }

    // main loop: rows 0..55 — wait row r landed (<=7 outstanding), compute,
    // then refill the freed slot with row r+8.
    for (int r = 0; r < ROWS_PER_BLOCK - DEPTH; ++r) {
        asm volatile("s_waitcnt vmcnt(%0)" :: "i"(DEPTH - 1) : "memory");
        COMPUTE_ROW(r);
        load_to_lds16(xrow + (size_t)(r + DEPTH) * NALL,
                      ring_base + (r & (DEPTH - 1)) * 256);
    }
    // tail: everything issued; drain once, then consume rows 56..63.
    asm volatile("s_waitcnt vmcnt(0)" ::: "memory");
#pragma unroll
    for (int r = ROWS_PER_BLOCK - DEPTH; r < ROWS_PER_BLOCK; ++r)
        COMPUTE_ROW(r);

    // ---- phase 4: wave butterfly reduce (8 values x 6 steps) + atomics ----
#pragma unroll
    for (int c = 0; c < NCOL; ++c) {
#pragma unroll
        for (int off = 32; off >= 1; off >>= 1)
            acc[c] += __shfl_xor(acc[c], off, 64);
    }

    if (lane == 0) {
        const int q = ih + 2 * jh;
        float* o = out + (size_t)b * (4 * NCOL) + q * NCOL;
#pragma unroll
        for (int c = 0; c < NCOL; ++c)
            atomicAdd(o + c, acc[c]);
    }
}

extern "C" void kernel_launch(void* const* d_in, const int* in_sizes, int n_in,
                              void* d_out, int out_size, void* d_ws, size_t ws_size,
                              hipStream_t stream) {
    const float* x = (const float*)d_in[0];
    const float* u = (const float*)d_in[1];
    const float* v = (const float*)d_in[2];
    float* out = (float*)d_out;

    const int b_count = in_sizes[0] / (NALL * NALL);   // 128

    // zero the accumulated output every call (atomics accumulate into it)
    (void)hipMemsetAsync(d_out, 0, (size_t)out_size * sizeof(float), stream);

    dim3 grid(b_count * CHUNKS);
    jxy_kernel<<<grid, THREADS, 0, stream>>>(x, u, v, out);
}

// Round 5
// 109.859 us; speedup vs baseline: 1.1531x; 1.1531x over previous
//
#include <hip/hip_runtime.h>

#define NALL 1024
#define NH   512
#define NCOL 8
#define ROWS_PER_BLOCK 64
#define THREADS 256
#define CHUNKS (NALL / ROWS_PER_BLOCK)   // 16
#define BATCH 16                         // rows loaded per register batch

typedef float f32x4 __attribute__((ext_vector_type(4)));

// Fused kernel: per-block recompute of joint column norms of concat(u,v)
// (32 KB, L2-resident after first block -> ~free, paid in parallel by all
// blocks at launch), then streaming quadratic-form reduction over this
// block's 64 rows of one sample's 1024x1024 Jacobian.
// x is loaded in 16-deep register batches (64 VGPRs of in-flight data) to
// maximize memory-level parallelism; nontemporal (x >> L3, read once).
// out[b][q*8+c], q = ih + 2*jh:
//   q0 = uJu (i<512, j<512),  q1 = vJu (i>=512, j<512),
//   q2 = uJv (i<512, j>=512), q3 = vJv (i>=512, j>=512)
__global__ __launch_bounds__(THREADS, 4) void jxy_kernel(
    const float* __restrict__ x, const float* __restrict__ u,
    const float* __restrict__ v, float* __restrict__ out) {
    const int bid   = blockIdx.x;
    const int b     = bid >> 4;          // sample
    const int chunk = bid & (CHUNKS - 1);
    const int r0    = chunk * ROWS_PER_BLOCK;
    const int ih    = (r0 >= NH) ? 1 : 0;   // 64-row chunks never straddle halves
    const int rloc  = r0 - ih * NH;

    const int tid  = threadIdx.x;
    const int wave = tid >> 6;
    const int lane = tid & 63;
    const int jbase = wave * 256 + lane * 4;   // this lane's 4 fixed j positions
    const int jh    = (jbase >= NH) ? 1 : 0;   // uniform per wave
    const int jloc  = jbase - jh * NH;

    // ---- phase 1: joint column norms of concat(u,v) ----
    __shared__ float red[THREADS];
    __shared__ float inv_norm[NCOL];
    {
        const int c   = tid & 7;
        const int seg = tid >> 3;    // 0..31
        float s = 0.f;
        for (int r = seg; r < NH; r += 32) {
            float a = u[r * NCOL + c];
            float bb = v[r * NCOL + c];
            s = fmaf(a, a, fmaf(bb, bb, s));
        }
        red[tid] = s;
        __syncthreads();
        for (int off = THREADS / 2; off >= NCOL; off >>= 1) {
            if (tid < off) red[tid] += red[tid + off];
            __syncthreads();
        }
        if (tid < NCOL) inv_norm[tid] = 1.0f / sqrtf(red[tid]);
        __syncthreads();
    }

    // ---- phase 2: stage normalized left rows (LDS) + right fragment (regs) ----
    __shared__ __align__(16) float wl[ROWS_PER_BLOCK * NCOL];
    const float* rawl = ih ? v : u;
    for (int idx = tid; idx < ROWS_PER_BLOCK * NCOL; idx += THREADS)
        wl[idx] = rawl[rloc * NCOL + idx] * inv_norm[idx & 7];

    const float* rawr = jh ? v : u;
    float wr[4][NCOL];
#pragma unroll
    for (int k = 0; k < 4; ++k) {
        const float4* p = reinterpret_cast<const float4*>(rawr + (size_t)(jloc + k) * NCOL);
        float4 a = p[0];
        float4 bq = p[1];
        wr[k][0] = a.x * inv_norm[0];  wr[k][1] = a.y * inv_norm[1];
        wr[k][2] = a.z * inv_norm[2];  wr[k][3] = a.w * inv_norm[3];
        wr[k][4] = bq.x * inv_norm[4]; wr[k][5] = bq.y * inv_norm[5];
        wr[k][6] = bq.z * inv_norm[6]; wr[k][7] = bq.w * inv_norm[7];
    }
    __syncthreads();

    // ---- phase 3: stream 64 rows of x in 16-deep register batches ----
    float acc[NCOL];
#pragma unroll
    for (int c = 0; c < NCOL; ++c) acc[c] = 0.f;

    const float* xrow = x + ((size_t)b * NALL + r0) * NALL + jbase;

    for (int rb = 0; rb < ROWS_PER_BLOCK; rb += BATCH) {
        f32x4 xv[BATCH];
        // issue all 16 loads back-to-back (64 VGPRs in flight)
#pragma unroll
        for (int k = 0; k < BATCH; ++k)
            xv[k] = __builtin_nontemporal_load(
                reinterpret_cast<const f32x4*>(xrow + (size_t)(rb + k) * NALL));

#pragma unroll
        for (int k = 0; k < BATCH; ++k) {
            float t[NCOL];
#pragma unroll
            for (int c = 0; c < NCOL; ++c)
                t[c] = fmaf(xv[k].x, wr[0][c],
                       fmaf(xv[k].y, wr[1][c],
                       fmaf(xv[k].z, wr[2][c],
                            xv[k].w * wr[3][c])));

            // wave-uniform broadcast reads from LDS (no bank conflict)
            float4 wa = *reinterpret_cast<const float4*>(&wl[(rb + k) * NCOL]);
            float4 wb = *reinterpret_cast<const float4*>(&wl[(rb + k) * NCOL + 4]);
            acc[0] = fmaf(wa.x, t[0], acc[0]);
            acc[1] = fmaf(wa.y, t[1], acc[1]);
            acc[2] = fmaf(wa.z, t[2], acc[2]);
            acc[3] = fmaf(wa.w, t[3], acc[3]);
            acc[4] = fmaf(wb.x, t[4], acc[4]);
            acc[5] = fmaf(wb.y, t[5], acc[5]);
            acc[6] = fmaf(wb.z, t[6], acc[6]);
            acc[7] = fmaf(wb.w, t[7], acc[7]);
        }
    }

    // ---- phase 4: wave butterfly reduce (8 values x 6 steps) + atomics ----
#pragma unroll
    for (int c = 0; c < NCOL; ++c) {
#pragma unroll
        for (int off = 32; off >= 1; off >>= 1)
            acc[c] += __shfl_xor(acc[c], off, 64);
    }

    if (lane == 0) {
        const int q = ih + 2 * jh;
        float* o = out + (size_t)b * (4 * NCOL) + q * NCOL;
#pragma unroll
        for (int c = 0; c < NCOL; ++c)
            atomicAdd(o + c, acc[c]);
    }
}

extern "C" void kernel_launch(void* const* d_in, const int* in_sizes, int n_in,
                              void* d_out, int out_size, void* d_ws, size_t ws_size,
                              hipStream_t stream) {
    const float* x = (const float*)d_in[0];
    const float* u = (const float*)d_in[1];
    const float* v = (const float*)d_in[2];
    float* out = (float*)d_out;

    const int b_count = in_sizes[0] / (NALL * NALL);   // 128

    // zero the accumulated output every call (atomics accumulate into it)
    (void)hipMemsetAsync(d_out, 0, (size_t)out_size * sizeof(float), stream);

    dim3 grid(b_count * CHUNKS);
    jxy_kernel<<<grid, THREADS, 0, stream>>>(x, u, v, out);
}

// Round 6
// 96.128 us; speedup vs baseline: 1.3179x; 1.1428x over previous
//
#include <hip/hip_runtime.h>

#define NALL 1024
#define NH   512
#define NCOL 8
#define ROWS_PER_BLOCK 64
#define THREADS 256
#define CHUNKS (NALL / ROWS_PER_BLOCK)   // 16
#define SAMPLES 2                        // samples per block (amortize prologue)

typedef float f32x4 __attribute__((ext_vector_type(4)));

// Fused kernel. Each block owns (sample-pair, 64-row chunk). Prologue
// (joint column norms of concat(u,v), normalized left rows in LDS, right
// fragment in regs) is sample-independent -> computed once, then the block
// streams 2 samples' worth of x rows (512 KB). grid = 1024 = one resident
// generation at 4 blocks/CU -> prologue paid once, in parallel, everywhere.
// out[b][q*8+c], q = ih + 2*jh:
//   q0 = uJu (i<512, j<512),  q1 = vJu (i>=512, j<512),
//   q2 = uJv (i<512, j>=512), q3 = vJv (i>=512, j>=512)
__global__ __launch_bounds__(THREADS) void jxy_kernel(
    const float* __restrict__ x, const float* __restrict__ u,
    const float* __restrict__ v, float* __restrict__ out) {
    const int bid   = blockIdx.x;
    const int pair  = bid >> 4;          // sample pair index
    const int chunk = bid & (CHUNKS - 1);
    const int r0    = chunk * ROWS_PER_BLOCK;
    const int ih    = (r0 >= NH) ? 1 : 0;   // 64-row chunks never straddle halves
    const int rloc  = r0 - ih * NH;

    const int tid  = threadIdx.x;
    const int wave = tid >> 6;
    const int lane = tid & 63;
    const int jbase = wave * 256 + lane * 4;   // this lane's 4 fixed j positions
    const int jh    = (jbase >= NH) ? 1 : 0;   // uniform per wave
    const int jloc  = jbase - jh * NH;

    // ---- phase 1: joint column norms of concat(u,v) ----
    __shared__ float red[THREADS];
    __shared__ float inv_norm[NCOL];
    {
        const int c   = tid & 7;
        const int seg = tid >> 3;    // 0..31
        float s = 0.f;
        for (int r = seg; r < NH; r += 32) {
            float a = u[r * NCOL + c];
            float bb = v[r * NCOL + c];
            s = fmaf(a, a, fmaf(bb, bb, s));
        }
        red[tid] = s;
        __syncthreads();
        for (int off = THREADS / 2; off >= NCOL; off >>= 1) {
            if (tid < off) red[tid] += red[tid + off];
            __syncthreads();
        }
        if (tid < NCOL) inv_norm[tid] = 1.0f / sqrtf(red[tid]);
        __syncthreads();
    }

    // ---- phase 2: stage normalized left rows (LDS) + right fragment (regs) ----
    __shared__ __align__(16) float wl[ROWS_PER_BLOCK * NCOL];
    const float* rawl = ih ? v : u;
    for (int idx = tid; idx < ROWS_PER_BLOCK * NCOL; idx += THREADS)
        wl[idx] = rawl[rloc * NCOL + idx] * inv_norm[idx & 7];

    const float* rawr = jh ? v : u;
    float wr[4][NCOL];
#pragma unroll
    for (int k = 0; k < 4; ++k) {
        const float4* p = reinterpret_cast<const float4*>(rawr + (size_t)(jloc + k) * NCOL);
        float4 a = p[0];
        float4 bq = p[1];
        wr[k][0] = a.x * inv_norm[0];  wr[k][1] = a.y * inv_norm[1];
        wr[k][2] = a.z * inv_norm[2];  wr[k][3] = a.w * inv_norm[3];
        wr[k][4] = bq.x * inv_norm[4]; wr[k][5] = bq.y * inv_norm[5];
        wr[k][6] = bq.z * inv_norm[6]; wr[k][7] = bq.w * inv_norm[7];
    }
    __syncthreads();

    // ---- phase 3+4 per sample: stream 64 rows, reduce, one atomic set ----
    for (int s = 0; s < SAMPLES; ++s) {
        const int b = pair * SAMPLES + s;

        float acc[NCOL];
#pragma unroll
        for (int c = 0; c < NCOL; ++c) acc[c] = 0.f;

        const float* xrow = x + ((size_t)b * NALL + r0) * NALL + jbase;

#pragma unroll 8
        for (int r = 0; r < ROWS_PER_BLOCK; ++r) {
            f32x4 xv = __builtin_nontemporal_load(
                reinterpret_cast<const f32x4*>(xrow + (size_t)r * NALL));

            float t[NCOL];
#pragma unroll
            for (int c = 0; c < NCOL; ++c)
                t[c] = fmaf(xv.x, wr[0][c],
                       fmaf(xv.y, wr[1][c],
                       fmaf(xv.z, wr[2][c],
                            xv.w * wr[3][c])));

            // wave-uniform broadcast reads from LDS (no bank conflict)
            float4 wa = *reinterpret_cast<const float4*>(&wl[r * NCOL]);
            float4 wb = *reinterpret_cast<const float4*>(&wl[r * NCOL + 4]);
            acc[0] = fmaf(wa.x, t[0], acc[0]);
            acc[1] = fmaf(wa.y, t[1], acc[1]);
            acc[2] = fmaf(wa.z, t[2], acc[2]);
            acc[3] = fmaf(wa.w, t[3], acc[3]);
            acc[4] = fmaf(wb.x, t[4], acc[4]);
            acc[5] = fmaf(wb.y, t[5], acc[5]);
            acc[6] = fmaf(wb.z, t[6], acc[6]);
            acc[7] = fmaf(wb.w, t[7], acc[7]);
        }

        // wave butterfly reduce (8 values x 6 steps)
#pragma unroll
        for (int c = 0; c < NCOL; ++c) {
#pragma unroll
            for (int off = 32; off >= 1; off >>= 1)
                acc[c] += __shfl_xor(acc[c], off, 64);
        }

        if (lane == 0) {
            const int q = ih + 2 * jh;
            float* o = out + (size_t)b * (4 * NCOL) + q * NCOL;
#pragma unroll
            for (int c = 0; c < NCOL; ++c)
                atomicAdd(o + c, acc[c]);
        }
    }
}

extern "C" void kernel_launch(void* const* d_in, const int* in_sizes, int n_in,
                              void* d_out, int out_size, void* d_ws, size_t ws_size,
                              hipStream_t stream) {
    const float* x = (const float*)d_in[0];
    const float* u = (const float*)d_in[1];
    const float* v = (const float*)d_in[2];
    float* out = (float*)d_out;

    const int b_count = in_sizes[0] / (NALL * NALL);   // 128

    // zero the accumulated output every call (atomics accumulate into it)
    (void)hipMemsetAsync(d_out, 0, (size_t)out_size * sizeof(float), stream);

    dim3 grid((b_count / SAMPLES) * CHUNKS);   // 1024
    jxy_kernel<<<grid, THREADS, 0, stream>>>(x, u, v, out);
}